// Round 5
// baseline (205.337 us; speedup 1.0000x reference)
//
#include <hip/hip_runtime.h>
#include <math.h>
#include <stdint.h>

#define NUMCH 65
#define THREADS 256
#define WAVES 4
#define NTILE 4
#define CTILE 1024
#define TILE_T (NTILE * CTILE)   // 4096
#define NGRP 32
#define PLEN 960                 // max piece taps -> nc <= 62
#define MAXP 224

#define XR 10                    // x prefetch rounds (XDWn <= 2560 = 10*256)
#define WR 5                     // w prefetch rounds (WB <= 1040 <= 1280)
#define XPHYS 2720               // SW2(2559)+1 rounded
#define WBMAX 1056
#define SMEM_DW (2 * XPHYS + WBMAX)   // 6496 dwords = 26 KB
#define RSTRIDE 1184             // SW5(1023)+1 rounded; 4*1184=4736 <= SMEM_DW

#define SW2(d) ((d) + ((((d) >> 5)) << 1))
#define SW5(d) ((d) + ((d) >> 5) * 5)

struct PTab {
  short c[MAXP], ka[MAXP], len[MAXP], nc[MAXP];
  int start[NGRP + 1];
};

typedef short bf16x8 __attribute__((ext_vector_type(8)));
typedef float f32x16 __attribute__((ext_vector_type(16)));

__global__ void zero_kernel(float* __restrict__ out, int n)
{
  int i = blockIdx.x * blockDim.x + threadIdx.x;
  if (i < n) out[i] = 0.0f;
}

__device__ __forceinline__ uint32_t f2bf(float f) {
  uint32_t u = __float_as_uint(f);
  return (u + 0x7FFFu + ((u >> 16) & 1u)) >> 16;
}
__device__ __forceinline__ void splithl(float v, uint32_t& h, uint32_t& l) {
  h = f2bf(v);
  l = f2bf(v - __uint_as_float(h << 16));
}
__device__ __forceinline__ uint32_t packhl(float v) {
  uint32_t h, l;
  splithl(v, h, l);
  return h | (l << 16);
}

struct Ctx {
  int ka, len, nc, X0, XDWn, WB;
  const float* xc;
  const float* wc;
};

// out[b,t] += (1/fs) * sum_c sum_k w[c,k] * x[b,c, t + off_c + k]
// Per chunk ci, tile tau:  C[i][j] += sum_kk A[i][kk]*B[kk][j]
//   A[i][kk] = w[ka+16ci+kk-i] (Toeplitz band), B[kk][j] = x[X0 + 1024tau + 32j + 16ci + kk]
//   C[i][j] -> out[t0 + 1024tau + 32j + i]
__global__ __launch_bounds__(THREADS, 4)
void conv_mfma_kernel(const float* __restrict__ inp, const float* __restrict__ w,
                      const int* __restrict__ gidx, const int* __restrict__ fsp,
                      float* __restrict__ out, PTab P, int B, int T, int K)
{
  __shared__ __align__(16) uint32_t smem[SMEM_DW];
  uint32_t* xh = smem;                 // packed bf16 h-plane (2 el/dword), SW2 swizzle
  uint32_t* xl = smem + XPHYS;         // packed bf16 l-plane
  uint32_t* wband = smem + 2 * XPHYS;  // per element: h | l<<16

  const int g = blockIdx.x, tile4 = blockIdx.y, b = blockIdx.z;
  const int tid = threadIdx.x;
  const int lane = tid & 63;
  const int wv = tid >> 6;
  const int col = lane & 31;
  const int half = lane >> 5;
  const int t0 = tile4 * TILE_T;

  const int piBeg = P.start[g], piEnd = P.start[g + 1];

  f32x16 acc[NTILE];
  #pragma unroll
  for (int t = 0; t < NTILE; ++t)
    #pragma unroll
    for (int i = 0; i < 16; ++i) acc[t][i] = 0.0f;

  float2 xp[XR];
  float wp[WR];

  // ---- piece context + prefetch helpers (inlined lambdas) ----
  auto make_ctx = [&](int pi) -> Ctx {
    Ctx c;
    c.ka = P.ka[pi]; c.len = P.len[pi]; c.nc = P.nc[pi];
    const int ch = P.c[pi];
    const int start_c = gidx[(size_t)ch * T];
    const int off = start_c - (K - 1);
    c.X0 = t0 + off + c.ka;
    const int EN = 16 * c.nc + TILE_T + 32;
    c.XDWn = (EN + 1) >> 1;
    c.WB = 16 * c.nc + 48;
    c.xc = inp + ((size_t)b * (2 * NUMCH) + ch) * T;
    c.wc = w + (size_t)ch * K;
    return c;
  };
  auto prefetch = [&](const Ctx& c) {
    #pragma unroll
    for (int r = 0; r < XR; ++r) {
      const int d = tid + THREADS * r;
      float2 v; v.x = 0.0f; v.y = 0.0f;
      if (d < c.XDWn) {
        const int gi0 = c.X0 + 2 * d;
        if (gi0 >= 0 && gi0 < T) v.x = c.xc[gi0];
        if (gi0 + 1 >= 0 && gi0 + 1 < T) v.y = c.xc[gi0 + 1];
      }
      xp[r] = v;
    }
    #pragma unroll
    for (int r = 0; r < WR; ++r) {
      const int d = tid + THREADS * r;
      float v = 0.0f;
      if (d >= 32 && d < c.WB) {
        const int k = c.ka + d - 32;
        if (k < c.ka + c.len) v = c.wc[k];
      }
      wp[r] = v;
    }
  };
  auto stage = [&](const Ctx& c) {
    #pragma unroll
    for (int r = 0; r < XR; ++r) {
      const int d = tid + THREADS * r;
      if (d < c.XDWn) {
        uint32_t h0, l0, h1, l1;
        splithl(xp[r].x, h0, l0);
        splithl(xp[r].y, h1, l1);
        const int pd = SW2(d);
        xh[pd] = h0 | (h1 << 16);
        xl[pd] = l0 | (l1 << 16);
      }
    }
    #pragma unroll
    for (int r = 0; r < WR; ++r) {
      const int d = tid + THREADS * r;
      if (d < c.WB) wband[d] = packhl(wp[r]);
    }
  };

  if (piBeg < piEnd) {
    Ctx cur = make_ctx(piBeg);
    prefetch(cur);
    for (int pi = piBeg; pi < piEnd; ++pi) {
      __syncthreads();            // previous piece's LDS consumers done
      stage(cur);
      __syncthreads();
      Ctx nxt;
      if (pi + 1 < piEnd) { nxt = make_ctx(pi + 1); prefetch(nxt); }
      const int nc = cur.nc;
      for (int ci = wv; ci < nc; ci += WAVES) {
        // A fragment: 8 hl-dwords (lane-stride -1, conflict-free), unpack amortized over 4 tiles
        const int abase = 32 + 16 * ci + 8 * half - col;
        uint32_t ad[8];
        #pragma unroll
        for (int j = 0; j < 8; ++j) ad[j] = wband[abase + j];
        union AU { uint32_t u[4]; bf16x8 v; } Ah, Al;
        #pragma unroll
        for (int j = 0; j < 4; ++j) {
          const uint32_t a0 = ad[2 * j], a1 = ad[2 * j + 1];
          Ah.u[j] = (a0 & 0xFFFFu) | (a1 << 16);
          Al.u[j] = (a0 >> 16) | (a1 & 0xFFFF0000u);
        }
        const int dbase = 16 * col + 4 * half + 8 * ci;
        #pragma unroll
        for (int tau = 0; tau < NTILE; ++tau) {
          const int d0 = 512 * tau + dbase;       // 4-aligned logical dword
          const int p0 = SW2(d0);                 // d0..d0+3 share swizzle offset
          union BU { uint2 q[2]; bf16x8 v; } Bh, Bl;
          Bh.q[0] = *(const uint2*)&xh[p0];
          Bh.q[1] = *(const uint2*)&xh[p0 + 2];
          Bl.q[0] = *(const uint2*)&xl[p0];
          Bl.q[1] = *(const uint2*)&xl[p0 + 2];
          acc[tau] = __builtin_amdgcn_mfma_f32_32x32x16_bf16(Ah.v, Bh.v, acc[tau], 0, 0, 0);
          acc[tau] = __builtin_amdgcn_mfma_f32_32x32x16_bf16(Ah.v, Bl.v, acc[tau], 0, 0, 0);
          acc[tau] = __builtin_amdgcn_mfma_f32_32x32x16_bf16(Al.v, Bh.v, acc[tau], 0, 0, 0);
        }
      }
      cur = nxt;
    }
  }

  // epilogue: per tile, cross-wave LDS reduce + one atomicAdd per output
  __syncthreads();
  const float inv_fs = 1.0f / (float)fsp[0];
  for (int tau = 0; tau < NTILE; ++tau) {
    #pragma unroll
    for (int r = 0; r < 16; ++r) {
      const int row = (r & 3) + 8 * (r >> 2) + 4 * half;   // verified C/D layout
      const int tl = 32 * col + row;
      smem[wv * RSTRIDE + SW5(tl)] = __float_as_uint(acc[tau][r]);
    }
    __syncthreads();
    for (int i = tid; i < CTILE; i += THREADS) {
      const int pidx = SW5(i);
      float s = __uint_as_float(smem[pidx]) +
                __uint_as_float(smem[RSTRIDE + pidx]) +
                __uint_as_float(smem[2 * RSTRIDE + pidx]) +
                __uint_as_float(smem[3 * RSTRIDE + pidx]);
      atomicAdd(&out[(size_t)b * T + t0 + tau * CTILE + i], s * inv_fs);
    }
    __syncthreads();
  }
}

extern "C" void kernel_launch(void* const* d_in, const int* in_sizes, int n_in,
                              void* d_out, int out_size, void* d_ws, size_t ws_size,
                              hipStream_t stream)
{
  const float* inp = (const float*)d_in[0];
  const float* wgt = (const float*)d_in[1];
  const int* gidx  = (const int*)d_in[2];
  const int* fsp   = (const int*)d_in[3];
  float* out = (float*)d_out;

  const int K = in_sizes[1] / NUMCH;
  const int T = in_sizes[2] / NUMCH;
  const int B = in_sizes[0] / (2 * NUMCH * T);

  // ---- host-side piece construction (analytic gammatone lengths, 48-tap margin) ----
  const double a = pow(10.0, 1.0 / 32.0);
  int pC[MAXP], pKa[MAXP], pLen[MAXP], pNc[MAXP];
  double pW[MAXP];
  int np_ = 0;
  for (int c = 0; c < NUMCH; ++c) {
    int gl = (int)ceil((K / 10.0) * pow(a, 32.0 - c) - 1e-9);
    if (gl > K) gl = K;
    int k0 = K - gl - 48; if (k0 < 0) k0 = 0;
    const int len = K - k0;
    const int npc = (len + PLEN - 1) / PLEN;
    int plen = (len + npc - 1) / npc;
    plen = (plen + 15) & ~15;
    if (plen > PLEN) plen = PLEN;
    for (int i = 0; i < npc && np_ < MAXP; ++i) {
      const int kai = k0 + i * plen;
      if (kai >= K) break;
      const int li = (K - kai < plen) ? (K - kai) : plen;
      pC[np_] = c; pKa[np_] = kai; pLen[np_] = li;
      pNc[np_] = (li + 15) / 16 + 2;
      pW[np_] = (double)pNc[np_] + 6.0;
      ++np_;
    }
  }
  for (int i = 1; i < np_; ++i) {
    int c = pC[i], ka = pKa[i], ln = pLen[i], nc = pNc[i];
    double wv = pW[i];
    int j = i - 1;
    while (j >= 0 && pW[j] < wv) {
      pC[j+1]=pC[j]; pKa[j+1]=pKa[j]; pLen[j+1]=pLen[j]; pNc[j+1]=pNc[j]; pW[j+1]=pW[j]; --j;
    }
    pC[j+1]=c; pKa[j+1]=ka; pLen[j+1]=ln; pNc[j+1]=nc; pW[j+1]=wv;
  }
  double gsum[NGRP]; int gcnt[NGRP];
  static int glist[NGRP][MAXP];
  for (int g = 0; g < NGRP; ++g) { gsum[g] = 0.0; gcnt[g] = 0; }
  for (int i = 0; i < np_; ++i) {
    int best = 0;
    for (int g = 1; g < NGRP; ++g) if (gsum[g] < gsum[best]) best = g;
    glist[best][gcnt[best]++] = i;
    gsum[best] += pW[i];
  }
  PTab P;
  int p = 0;
  P.start[0] = 0;
  for (int g = 0; g < NGRP; ++g) {
    for (int i = 0; i < gcnt[g]; ++i) {
      const int id = glist[g][i];
      P.c[p] = (short)pC[id]; P.ka[p] = (short)pKa[id];
      P.len[p] = (short)pLen[id]; P.nc[p] = (short)pNc[id];
      ++p;
    }
    P.start[g + 1] = p;
  }
  for (int i = p; i < MAXP; ++i) { P.c[i] = 0; P.ka[i] = 0; P.len[i] = 0; P.nc[i] = 0; }

  zero_kernel<<<(out_size + 255) / 256, 256, 0, stream>>>(out, out_size);
  dim3 grid(NGRP, T / TILE_T, B);
  conv_mfma_kernel<<<grid, THREADS, 0, stream>>>(inp, wgt, gidx, fsp, out, P, B, T, K);
}

// Round 6
// 188.016 us; speedup vs baseline: 1.0921x; 1.0921x over previous
//
#include <hip/hip_runtime.h>
#include <math.h>
#include <stdint.h>

#define NUMCH 65
#define THREADS 256
#define WAVES 4
#define NTILE 2
#define CTILE 1024
#define TILE_T (NTILE * CTILE)   // 2048
#define NGRP 32
#define PLEN 1024                // max piece taps -> nc <= 66
#define MAXP 224

#define XPHYS 1764               // SW4(1567)+pad; XDWn <= 1568
#define WBMAX 1104
#define RSTRIDE 1184             // SW5(1023)+pad
#define SMEM_DW 4736             // max(2*1764+1104=4632, 4*1184=4736)

#define SW4(d) ((d) + ((((d) >> 5)) << 2))
#define SW5(d) ((d) + ((d) >> 5) * 5)

struct PTab {
  short c[MAXP], ka[MAXP], len[MAXP], nc[MAXP];
  int start[NGRP + 1];
};

typedef short bf16x8 __attribute__((ext_vector_type(8)));
typedef float f32x16 __attribute__((ext_vector_type(16)));

__global__ void zero_kernel(float* __restrict__ out, int n)
{
  int i = blockIdx.x * blockDim.x + threadIdx.x;
  if (i < n) out[i] = 0.0f;
}

__device__ __forceinline__ uint32_t f2bf(float f) {
  uint32_t u = __float_as_uint(f);
  return (u + 0x7FFFu + ((u >> 16) & 1u)) >> 16;
}
__device__ __forceinline__ void splithl(float v, uint32_t& h, uint32_t& l) {
  h = f2bf(v);
  l = f2bf(v - __uint_as_float(h << 16));
}
__device__ __forceinline__ uint32_t packhl(float v) {
  uint32_t h, l;
  splithl(v, h, l);
  return h | (l << 16);
}

// out[b,t] += (1/fs) * sum_c sum_k w[c,k] * x[b,c, t + off_c + k]
// Per chunk ci, tile tau:  C[i][j] += sum_kk A[i][kk]*B[kk][j]
//   A[i][kk] = w[ka+16ci+kk-i] (Toeplitz band), B[kk][j] = x[X0 + 1024tau + 32j + 16ci + kk]
//   C[i][j] -> out[t0 + 1024tau + 32j + i]
__global__ __launch_bounds__(THREADS, 5)
void conv_mfma_kernel(const float* __restrict__ inp, const float* __restrict__ w,
                      const int* __restrict__ gidx, const int* __restrict__ fsp,
                      float* __restrict__ out, PTab P, int B, int T, int K)
{
  __shared__ __align__(16) uint32_t smem[SMEM_DW];
  uint32_t* xh = smem;                 // packed bf16 h-plane (2 el/dword), SW4 swizzle
  uint32_t* xl = smem + XPHYS;         // packed bf16 l-plane
  uint32_t* wband = smem + 2 * XPHYS;  // per element: h | l<<16

  const int g = blockIdx.x, tileg = blockIdx.y, b = blockIdx.z;
  const int tid = threadIdx.x;
  const int lane = tid & 63;
  const int wv = tid >> 6;
  const int col = lane & 31;
  const int half = lane >> 5;
  const int t0 = tileg * TILE_T;

  f32x16 acc[NTILE];
  #pragma unroll
  for (int t = 0; t < NTILE; ++t)
    #pragma unroll
    for (int i = 0; i < 16; ++i) acc[t][i] = 0.0f;

  for (int pi = P.start[g]; pi < P.start[g + 1]; ++pi) {
    const int c   = P.c[pi];
    const int ka  = P.ka[pi];
    const int len = P.len[pi];
    const int nc  = P.nc[pi];
    const int EN  = 16 * nc + TILE_T + 32;
    const int XDWn = (EN + 1) >> 1;
    const int WB  = 16 * nc + 48;
    const int start_c = gidx[(size_t)c * T];
    const int off = start_c - (K - 1);
    const int X0 = t0 + off + ka;
    const float* __restrict__ xc = inp + ((size_t)b * (2 * NUMCH) + c) * T;
    const float* __restrict__ wc = w + (size_t)c * K;

    __syncthreads();
    // stage x: split into h/l planes, 2 elements per dword, SW4 swizzle.
    // Fast path when the whole window is interior (no per-element bounds tests).
    if (X0 >= 0 && X0 + 2 * XDWn <= T) {
      const float* __restrict__ xb = xc + X0;
      for (int d = tid; d < XDWn; d += THREADS) {
        const float2 v = *(const float2*)&xb[2 * d];
        uint32_t h0, l0, h1, l1;
        splithl(v.x, h0, l0);
        splithl(v.y, h1, l1);
        const int pd = SW4(d);
        xh[pd] = h0 | (h1 << 16);
        xl[pd] = l0 | (l1 << 16);
      }
    } else {
      for (int d = tid; d < XDWn; d += THREADS) {
        const int gi0 = X0 + 2 * d, gi1 = gi0 + 1;
        const float v0 = (gi0 >= 0 && gi0 < T) ? xc[gi0] : 0.0f;
        const float v1 = (gi1 >= 0 && gi1 < T) ? xc[gi1] : 0.0f;
        uint32_t h0, l0, h1, l1;
        splithl(v0, h0, l0);
        splithl(v1, h1, l1);
        const int pd = SW4(d);
        xh[pd] = h0 | (h1 << 16);
        xl[pd] = l0 | (l1 << 16);
      }
    }
    // stage w band (dword per element; zero outside piece)
    for (int d = tid; d < WB; d += THREADS) {
      const int k = ka + d - 32;
      const float v = (d >= 32 && k < ka + len) ? wc[k] : 0.0f;
      wband[d] = packhl(v);
    }
    __syncthreads();

    for (int ci = wv; ci < nc; ci += WAVES) {
      // A fragment: 8 hl-dwords (descending stride-1 per half: at worst 2-way alias = free)
      const int abase = 32 + 16 * ci + 8 * half - col;
      uint32_t ad[8];
      #pragma unroll
      for (int j = 0; j < 8; ++j) ad[j] = wband[abase + j];
      union AU { uint32_t u[4]; bf16x8 v; } Ah, Al;
      #pragma unroll
      for (int j = 0; j < 4; ++j) {
        const uint32_t a0 = ad[2 * j], a1 = ad[2 * j + 1];
        Ah.u[j] = (a0 & 0xFFFFu) | (a1 << 16);
        Al.u[j] = (a0 >> 16) | (a1 & 0xFFFF0000u);
      }
      const int dbase = 16 * col + 4 * half + 8 * ci;
      #pragma unroll
      for (int tau = 0; tau < NTILE; ++tau) {
        const int d0 = 512 * tau + dbase;       // 4-aligned logical dword
        const int p0 = SW4(d0);                 // d0..d0+3 share swizzle offset
        union BU { uint4 q; bf16x8 v; } Bh, Bl;
        Bh.q = *(const uint4*)&xh[p0];
        Bl.q = *(const uint4*)&xl[p0];
        acc[tau] = __builtin_amdgcn_mfma_f32_32x32x16_bf16(Ah.v, Bh.v, acc[tau], 0, 0, 0);
        acc[tau] = __builtin_amdgcn_mfma_f32_32x32x16_bf16(Ah.v, Bl.v, acc[tau], 0, 0, 0);
        acc[tau] = __builtin_amdgcn_mfma_f32_32x32x16_bf16(Al.v, Bh.v, acc[tau], 0, 0, 0);
      }
    }
  }

  // epilogue: per tile, cross-wave LDS reduce + one atomicAdd per output
  __syncthreads();
  const float inv_fs = 1.0f / (float)fsp[0];
  for (int tau = 0; tau < NTILE; ++tau) {
    #pragma unroll
    for (int r = 0; r < 16; ++r) {
      const int row = (r & 3) + 8 * (r >> 2) + 4 * half;   // verified C/D layout
      const int tl = 32 * col + row;
      smem[wv * RSTRIDE + SW5(tl)] = __float_as_uint(acc[tau][r]);
    }
    __syncthreads();
    for (int i = tid; i < CTILE; i += THREADS) {
      const int pidx = SW5(i);
      float s = __uint_as_float(smem[pidx]) +
                __uint_as_float(smem[RSTRIDE + pidx]) +
                __uint_as_float(smem[2 * RSTRIDE + pidx]) +
                __uint_as_float(smem[3 * RSTRIDE + pidx]);
      atomicAdd(&out[(size_t)b * T + t0 + tau * CTILE + i], s * inv_fs);
    }
    __syncthreads();
  }
}

extern "C" void kernel_launch(void* const* d_in, const int* in_sizes, int n_in,
                              void* d_out, int out_size, void* d_ws, size_t ws_size,
                              hipStream_t stream)
{
  const float* inp = (const float*)d_in[0];
  const float* wgt = (const float*)d_in[1];
  const int* gidx  = (const int*)d_in[2];
  const int* fsp   = (const int*)d_in[3];
  float* out = (float*)d_out;

  const int K = in_sizes[1] / NUMCH;
  const int T = in_sizes[2] / NUMCH;
  const int B = in_sizes[0] / (2 * NUMCH * T);

  // ---- host-side piece construction (analytic gammatone lengths, 48-tap margin) ----
  const double a = pow(10.0, 1.0 / 32.0);
  int pC[MAXP], pKa[MAXP], pLen[MAXP], pNc[MAXP];
  double pW[MAXP];
  int np_ = 0;
  for (int c = 0; c < NUMCH; ++c) {
    int gl = (int)ceil((K / 10.0) * pow(a, 32.0 - c) - 1e-9);
    if (gl > K) gl = K;
    int k0 = K - gl - 48; if (k0 < 0) k0 = 0;
    const int len = K - k0;
    const int npc = (len + PLEN - 1) / PLEN;
    int plen = (len + npc - 1) / npc;
    plen = (plen + 15) & ~15;
    if (plen > PLEN) plen = PLEN;
    for (int i = 0; i < npc && np_ < MAXP; ++i) {
      const int kai = k0 + i * plen;
      if (kai >= K) break;
      const int li = (K - kai < plen) ? (K - kai) : plen;
      pC[np_] = c; pKa[np_] = kai; pLen[np_] = li;
      pNc[np_] = (li + 15) / 16 + 2;
      pW[np_] = (double)pNc[np_] + 6.0;
      ++np_;
    }
  }
  for (int i = 1; i < np_; ++i) {
    int c = pC[i], ka = pKa[i], ln = pLen[i], nc = pNc[i];
    double wv = pW[i];
    int j = i - 1;
    while (j >= 0 && pW[j] < wv) {
      pC[j+1]=pC[j]; pKa[j+1]=pKa[j]; pLen[j+1]=pLen[j]; pNc[j+1]=pNc[j]; pW[j+1]=pW[j]; --j;
    }
    pC[j+1]=c; pKa[j+1]=ka; pLen[j+1]=ln; pNc[j+1]=nc; pW[j+1]=wv;
  }
  double gsum[NGRP]; int gcnt[NGRP];
  static int glist[NGRP][MAXP];
  for (int g = 0; g < NGRP; ++g) { gsum[g] = 0.0; gcnt[g] = 0; }
  for (int i = 0; i < np_; ++i) {
    int best = 0;
    for (int g = 1; g < NGRP; ++g) if (gsum[g] < gsum[best]) best = g;
    glist[best][gcnt[best]++] = i;
    gsum[best] += pW[i];
  }
  PTab P;
  int p = 0;
  P.start[0] = 0;
  for (int g = 0; g < NGRP; ++g) {
    for (int i = 0; i < gcnt[g]; ++i) {
      const int id = glist[g][i];
      P.c[p] = (short)pC[id]; P.ka[p] = (short)pKa[id];
      P.len[p] = (short)pLen[id]; P.nc[p] = (short)pNc[id];
      ++p;
    }
    P.start[g + 1] = p;
  }
  for (int i = p; i < MAXP; ++i) { P.c[i] = 0; P.ka[i] = 0; P.len[i] = 0; P.nc[i] = 0; }

  zero_kernel<<<(out_size + 255) / 256, 256, 0, stream>>>(out, out_size);
  dim3 grid(NGRP, T / TILE_T, B);
  conv_mfma_kernel<<<grid, THREADS, 0, stream>>>(inp, wgt, gidx, fsp, out, P, B, T, K);
}